// Round 3
// baseline (14.658 us; speedup 1.0000x reference)
//
#include <hip/hip_runtime.h>
#include <math.h>

typedef __attribute__((ext_vector_type(8))) short short8;   // 8 x bf16 (4 VGPR)
typedef __attribute__((ext_vector_type(4))) float f32x4;

#define L2E 1.44269504088896340736f
#define LN2 0.69314718055994530942f

// round-to-nearest-even float -> bf16 bits
static __device__ __forceinline__ unsigned int bfr(float x) {
    union { float f; unsigned u; } v; v.f = x;
    return (v.u + 0x7fffu + ((v.u >> 16) & 1u)) >> 16;
}
static __device__ __forceinline__ unsigned int pk2(float lo, float hi) {
    return bfr(lo) | (bfr(hi) << 16);
}

// out[b,f,co,r] = log( sum_ci w[f,ci,co,r] * exp(ll[b,f,ci,r]) )
// grid 1024 = f(128) x bq(4) x ch(2); block 256 = 4 waves; wave w handles r=w.
// Tile: 16 b x 32 co x 64 ci x 4 r.
__global__ __launch_bounds__(256, 4)
void ws_kernel(const float* __restrict__ ll,
               const float* __restrict__ wt,
               float* __restrict__ out)
{
    // bf16 operand tiles, 128B rows, XOR-swizzled ((row&7)<<4)
    __shared__ unsigned short Elds[4 * 16 * 64];   // 8 KB : E[r][b_local][ci]
    __shared__ unsigned short Wlds[4 * 32 * 64];   // 16 KB: Wt[r][co_local][ci]
    // epilogue transpose buffer aliases Elds/Wlds (16 rows x 132 dwords = 8448 B)
    float* Obuf = (float*)Elds;

    const int t   = threadIdx.x;
    const int blk = blockIdx.x;
    const int f   = blk >> 3;
    const int b0  = ((blk >> 1) & 3) * 16;
    const int co0 = (blk & 1) * 32;

    char* Ebase = (char*)Elds;
    char* Wbase = (char*)Wlds;

    // ---- stage E = bf16(exp(ll)) : thread owns (b, ci-pair), 2 b's ----
    {
        const float4* llv = (const float4*)ll;
        const int c  = t & 31;           // ci = 2c, 2c+1
        const int bb = t >> 5;           // 0..7
        #pragma unroll
        for (int k = 0; k < 2; ++k) {
            const int b = bb + 8 * k;    // 0..15
            const size_t base = (size_t)(b0 + b) * 8192 + (size_t)f * 64 + 2 * c;
            float4 v0 = llv[base];       // r = 0..3 of ci=2c
            float4 v1 = llv[base + 1];   // r = 0..3 of ci=2c+1
            float e0x = exp2f(v0.x * L2E), e0y = exp2f(v0.y * L2E),
                  e0z = exp2f(v0.z * L2E), e0w = exp2f(v0.w * L2E);
            float e1x = exp2f(v1.x * L2E), e1y = exp2f(v1.y * L2E),
                  e1z = exp2f(v1.z * L2E), e1w = exp2f(v1.w * L2E);
            const int off = (c * 4) ^ ((b & 7) << 4);
            char* rowp = Ebase + b * 128 + off;
            *(unsigned*)(rowp)        = pk2(e0x, e1x);   // r=0 plane (2 KB each)
            *(unsigned*)(rowp + 2048) = pk2(e0y, e1y);   // r=1
            *(unsigned*)(rowp + 4096) = pk2(e0z, e1z);   // r=2
            *(unsigned*)(rowp + 6144) = pk2(e0w, e1w);   // r=3
        }
    }
    // ---- stage Wt = bf16(w) transposed to [co][ci] : thread owns (co, ci-quad) ----
    {
        const float4* wv = (const float4*)wt;
        const int j = t & 31;            // co_local
        #pragma unroll
        for (int k = 0; k < 2; ++k) {
            const int cq = (t >> 5) + 8 * k;     // 0..15 ; ci = 4cq + i
            const size_t base = (size_t)f * 4096 + (size_t)(4 * cq) * 64 + co0 + j;
            float4 q0 = wv[base];
            float4 q1 = wv[base + 64];
            float4 q2 = wv[base + 128];
            float4 q3 = wv[base + 192];
            const int off = (cq * 8) ^ ((j & 7) << 4);
            char* rowp = Wbase + j * 128 + off;
            *(uint2*)(rowp)         = make_uint2(pk2(q0.x, q1.x), pk2(q2.x, q3.x));
            *(uint2*)(rowp + 4096)  = make_uint2(pk2(q0.y, q1.y), pk2(q2.y, q3.y));
            *(uint2*)(rowp + 8192)  = make_uint2(pk2(q0.z, q1.z), pk2(q2.z, q3.z));
            *(uint2*)(rowp + 12288) = make_uint2(pk2(q0.w, q1.w), pk2(q2.w, q3.w));
        }
    }
    __syncthreads();

    // ---- MFMA: wave r computes C[16b x 32co] = E_r(16x64) . Wt_r^T(64x32) ----
    const int r  = t >> 6;
    const int l  = t & 63;
    const int lr = l & 15;     // A-row / B-col within 16-tile
    const int lg = l >> 4;     // k-group (8 contiguous k each)
    const char* Ep = Ebase + r * 2048;
    const char* Wp = Wbase + r * 4096;

    f32x4 acc[2] = {{0.f,0.f,0.f,0.f},{0.f,0.f,0.f,0.f}};
    const int swz = (lr & 7) << 4;
    #pragma unroll
    for (int kt = 0; kt < 2; ++kt) {
        const int sb = ((kt * 4 + lg) * 16) ^ swz;   // byte offset of 16B chunk in row
        short8 a0 = *(const short8*)(Ep + lr * 128 + sb);
        short8 w0 = *(const short8*)(Wp + lr * 128 + sb);
        short8 w1 = *(const short8*)(Wp + (lr + 16) * 128 + sb);
        acc[0] = __builtin_amdgcn_mfma_f32_16x16x32_bf16(a0, w0, acc[0], 0, 0, 0);
        acc[1] = __builtin_amdgcn_mfma_f32_16x16x32_bf16(a0, w1, acc[1], 0, 0, 0);
    }

    __syncthreads();   // all MFMA LDS reads done before Obuf overwrite

    // ---- epilogue: acc -> LDS transpose -> coalesced float4 stores ----
    // Obuf rows: b (16), row stride 132 dwords (528 B, pad kills write conflicts)
    // D layout: col = lr, row = lg*4 + v (within 16x16 tile)
    #pragma unroll
    for (int nt = 0; nt < 2; ++nt) {
        #pragma unroll
        for (int v = 0; v < 4; ++v) {
            Obuf[(lg * 4 + v) * 132 + (nt * 16 + lr) * 4 + r] =
                __log2f(acc[nt][v]) * LN2;
        }
    }
    __syncthreads();

    // read back [b][co*4+r] rows (128 floats each) and store coalesced
    {
        const int row  = t >> 5;         // 0..7 (+8 on second pass)
        const int j    = t & 31;         // float4 column
        #pragma unroll
        for (int k = 0; k < 2; ++k) {
            const int b = row + 8 * k;
            float4 v = *(const float4*)&Obuf[b * 132 + j * 4];
            float* op = out + ((size_t)(b0 + b) * 128 + f) * 256 + (size_t)co0 * 4;
            *(float4*)(op + j * 4) = v;
        }
    }
}

extern "C" void kernel_launch(void* const* d_in, const int* in_sizes, int n_in,
                              void* d_out, int out_size, void* d_ws, size_t ws_size,
                              hipStream_t stream)
{
    const float* ll = (const float*)d_in[0];
    const float* wt = (const float*)d_in[1];
    float* out = (float*)d_out;
    hipLaunchKernelGGL(ws_kernel, dim3(1024), dim3(256), 0, stream, ll, wt, out);
}

// Round 4
// 10.853 us; speedup vs baseline: 1.3506x; 1.3506x over previous
//
#include <hip/hip_runtime.h>
#include <math.h>

typedef __attribute__((ext_vector_type(8))) short short8;   // 8 x bf16 (4 VGPR)
typedef __attribute__((ext_vector_type(4))) float f32x4;

#define L2E 1.44269504088896340736f
#define LN2 0.69314718055994530942f

// round-to-nearest-even float -> bf16 bits
static __device__ __forceinline__ unsigned int bfr(float x) {
    union { float f; unsigned u; } v; v.f = x;
    return (v.u + 0x7fffu + ((v.u >> 16) & 1u)) >> 16;
}
static __device__ __forceinline__ unsigned int pk2(float lo, float hi) {
    return bfr(lo) | (bfr(hi) << 16);
}

// out[b,f,co,r] = log( sum_ci w[f,ci,co,r] * exp(ll[b,f,ci,r]) )
// Tile: 16 b x 64 co x 64 ci x 4 r. Grid 512 = f(128) x bq(4), block 512 = 8 waves.
// Wave w: r = w&3, co-half = w>>2. ll fetched 1x, exp'd 1x; wt raw 4x/f but
// XCD-affine remap makes repeats L2-local.
__global__ __launch_bounds__(512, 4)
void ws_kernel(const float* __restrict__ ll,
               const float* __restrict__ wt,
               float* __restrict__ out)
{
    // E[4r][16b][64ci] bf16 @ 0 (8 KB), W[4r][64co][64ci] bf16 @ 8192 (32 KB)
    // 128B rows, XOR-swizzle ((row&7)<<4). Epilogue Obuf [16][260] f32 aliases smem.
    __shared__ char smem[8192 + 32768];
    float* Obuf = (float*)smem;

    const int t = threadIdx.x;

    // XCD-affine remap: dispatch i lands on XCD i%8; give each XCD whole f's
    const int i    = blockIdx.x;
    const int tile = (i & 7) * 64 + (i >> 3);
    const int f    = tile >> 2;
    const int b0   = (tile & 3) * 16;

    // ---- stage E = bf16(exp(ll)) : thread owns (b = t>>5, ci-pair c = t&31) ----
    {
        const float4* llv = (const float4*)ll;
        const int c = t & 31;
        const int b = t >> 5;
        const size_t base = (size_t)(b0 + b) * 8192 + (size_t)f * 64 + 2 * c;
        float4 v0 = llv[base];       // r=0..3 of ci=2c
        float4 v1 = llv[base + 1];   // r=0..3 of ci=2c+1
        float e0x = exp2f(v0.x * L2E), e0y = exp2f(v0.y * L2E),
              e0z = exp2f(v0.z * L2E), e0w = exp2f(v0.w * L2E);
        float e1x = exp2f(v1.x * L2E), e1y = exp2f(v1.y * L2E),
              e1z = exp2f(v1.z * L2E), e1w = exp2f(v1.w * L2E);
        const int off = (c * 4) ^ ((b & 7) << 4);
        char* rowp = smem + b * 128 + off;
        *(unsigned*)(rowp)        = pk2(e0x, e1x);   // r=0 plane (2 KB each)
        *(unsigned*)(rowp + 2048) = pk2(e0y, e1y);
        *(unsigned*)(rowp + 4096) = pk2(e0z, e1z);
        *(unsigned*)(rowp + 6144) = pk2(e0w, e1w);
    }
    // ---- stage Wt = bf16(w) -> [co][ci] : thread owns (co j = t&63, ci-oct c8 = t>>6) ----
    {
        const float4* wv = (const float4*)wt;
        const int j  = t & 63;
        const int c8 = t >> 6;
        const size_t base = (size_t)f * 4096 + (size_t)(8 * c8) * 64 + j;
        float4 q00 = wv[base];        // ci = 8c8+0
        float4 q01 = wv[base + 64];   // +1
        float4 q02 = wv[base + 128];  // +2
        float4 q03 = wv[base + 192];  // +3
        float4 q10 = wv[base + 256];  // +4
        float4 q11 = wv[base + 320];  // +5
        float4 q12 = wv[base + 384];  // +6
        float4 q13 = wv[base + 448];  // +7
        const int off = (c8 * 16) ^ ((j & 7) << 4);
        char* rowp = smem + 8192 + j * 128 + off;   // r=0 plane; planes 8 KB apart
        uint4 u;
        u.x = pk2(q00.x, q01.x); u.y = pk2(q02.x, q03.x);
        u.z = pk2(q10.x, q11.x); u.w = pk2(q12.x, q13.x);
        *(uint4*)(rowp) = u;
        u.x = pk2(q00.y, q01.y); u.y = pk2(q02.y, q03.y);
        u.z = pk2(q10.y, q11.y); u.w = pk2(q12.y, q13.y);
        *(uint4*)(rowp + 8192) = u;
        u.x = pk2(q00.z, q01.z); u.y = pk2(q02.z, q03.z);
        u.z = pk2(q10.z, q11.z); u.w = pk2(q12.z, q13.z);
        *(uint4*)(rowp + 16384) = u;
        u.x = pk2(q00.w, q01.w); u.y = pk2(q02.w, q03.w);
        u.z = pk2(q10.w, q11.w); u.w = pk2(q12.w, q13.w);
        *(uint4*)(rowp + 24576) = u;
    }
    __syncthreads();

    // ---- MFMA: wave (r, coh) computes C[16b x 32co] = E_r(16x64) . Wt_r^T(64x32) ----
    const int w   = t >> 6;
    const int l   = t & 63;
    const int r   = w & 3;
    const int coh = w >> 2;
    const int lr  = l & 15;     // A-row (b) / B-col (co) within 16-tile
    const int lg  = l >> 4;     // k-group (8 contiguous k each)
    const char* Ep = smem + r * 2048;
    const char* Wp = smem + 8192 + r * 8192 + coh * 4096;

    f32x4 acc[2] = {{0.f,0.f,0.f,0.f},{0.f,0.f,0.f,0.f}};
    const int swz = (lr & 7) << 4;
    #pragma unroll
    for (int kt = 0; kt < 2; ++kt) {
        const int sb = ((kt * 4 + lg) * 16) ^ swz;
        short8 a0 = *(const short8*)(Ep + lr * 128 + sb);
        short8 w0 = *(const short8*)(Wp + lr * 128 + sb);
        short8 w1 = *(const short8*)(Wp + (lr + 16) * 128 + sb);
        acc[0] = __builtin_amdgcn_mfma_f32_16x16x32_bf16(a0, w0, acc[0], 0, 0, 0);
        acc[1] = __builtin_amdgcn_mfma_f32_16x16x32_bf16(a0, w1, acc[1], 0, 0, 0);
    }

    __syncthreads();   // operand LDS dead before Obuf overwrite

    // ---- epilogue: log(acc) -> Obuf[b][co*4+r] (rows 260 dwords) ----
    // D layout (m89): col = lr, row = lg*4 + v
    #pragma unroll
    for (int nt = 0; nt < 2; ++nt) {
        #pragma unroll
        for (int v = 0; v < 4; ++v) {
            Obuf[(lg * 4 + v) * 260 + ((coh * 32 + nt * 16 + lr) * 4 + r)] =
                __log2f(acc[nt][v]) * LN2;
        }
    }
    __syncthreads();

    // ---- coalesced stores: each wave writes full 1 KB (b,f)-rows ----
    #pragma unroll
    for (int k = 0; k < 2; ++k) {
        const int b = w * 2 + k;
        float4 vv = *(const float4*)&Obuf[b * 260 + l * 4];
        *(float4*)(out + ((size_t)(b0 + b) * 128 + f) * 256 + l * 4) = vv;
    }
}

extern "C" void kernel_launch(void* const* d_in, const int* in_sizes, int n_in,
                              void* d_out, int out_size, void* d_ws, size_t ws_size,
                              hipStream_t stream)
{
    const float* ll = (const float*)d_in[0];
    const float* wt = (const float*)d_in[1];
    float* out = (float*)d_out;
    hipLaunchKernelGGL(ws_kernel, dim3(512), dim3(512), 0, stream, ll, wt, out);
}